// Round 8
// baseline (176.137 us; speedup 1.0000x reference)
//
#include <hip/hip_runtime.h>
#include <hip/hip_bf16.h>
#include <math.h>

// Problem constants (fixed by setup_inputs)
#define BATCH 4
#define NHEAD 8
#define HD 24          // head dim
#define CH 192         // total channels
#define HW 16384       // h*w
#define SPL 32         // kA col-blocks of 512 (2x256 cols accumulated in regs)
#define SROW 640       // Sp row: [0,576) gram, [576,600) sqq, [600,624) sqk, pad 640

// ws layout (floats):
//   Sp:  [32 bh][32 sp][640]   off 0        (2.62 MB)
//   Mo:  ushort[4][192][192]   off OFF_MO   (288 KB)
//   cnt: uint[32]              off OFF_CNT  (zeroed via tiny memset each launch)
//   kbf: bf16[32 bh][24][16384] off OFF_KBF (25.2 MB) — k pre-packed to bf16
#define OFF_MO  (32 * SPL * SROW)
#define OFF_CNT (OFF_MO + (BATCH * CH * CH) / 2)
#define OFF_KBF 729600   // floats; 16B-aligned

#define LSTR 132   // u32 per kA LDS row (128 data + 4 pad)

typedef __attribute__((ext_vector_type(8)))  short bf16x8;
typedef __attribute__((ext_vector_type(16))) float f32x16;

__device__ __forceinline__ unsigned short bf16rne(float x) {
    union { float f; unsigned u; } v; v.f = x;
    unsigned u = v.u;
    return (unsigned short)((u + 0x7FFFu + ((u >> 16) & 1u)) >> 16);
}

__device__ __forceinline__ unsigned pack2(float a, float b) {
    union { __hip_bfloat162 h; unsigned u; } c;
    c.h = __float22bfloat162_rn(float2{a, b});
    return c.u;
}

// Agent-scope RELAXED accessors (sc1, commit at L3; NO cache-flush fences).
__device__ __forceinline__ void st_agent(float* p, float v) {
    __hip_atomic_store(p, v, __ATOMIC_RELAXED, __HIP_MEMORY_SCOPE_AGENT);
}
__device__ __forceinline__ float ld_agent(const float* p) {
    return __hip_atomic_load(p, __ATOMIC_RELAXED, __HIP_MEMORY_SCOPE_AGENT);
}

// ---------------------------------------------------------------------------
// Kernel A + fenceless finalizer — R4 structure + kbf EXPORT: the bf16-packed
// k uint2s (already computed for LDS staging) are also stored to the kbf
// workspace (coalesced 512B segments), so kC never touches fp32 in2 again
// (halves kC's read bytes; bit-identical numerics).
// grid (32 bh, 32 cb), block 256, 4/CU.
// ---------------------------------------------------------------------------
__global__ __launch_bounds__(256, 4) void kA(const float* __restrict__ q,
                                             const float* __restrict__ k,
                                             const float* __restrict__ scale,
                                             const float* __restrict__ w,
                                             float* __restrict__ ws,
                                             unsigned short* __restrict__ Mo,
                                             unsigned int* __restrict__ cnt,
                                             unsigned int* __restrict__ kbf) {
    __shared__ unsigned int tile[2][HD * LSTR];   // 25.3 KB (reused by finalizer)
    __shared__ int lastFlag;

    const int bh   = blockIdx.x;
    const int cb   = blockIdx.y;      // 0..31 -> cols [cb*512, cb*512+512)
    const int t    = threadIdx.x;
    const int lane = t & 63;
    const int wave = t >> 6;
    const int m    = lane & 31;
    const int hi   = lane >> 5;
    const int rowc = (m < HD) ? m : 0;   // clamp: garbage only hits discarded C

    f32x16 aQK = {}, aQQ = {}, aKK = {};

    #pragma unroll
    for (int half = 0; half < 2; ++half) {
        const float* qb = q + (size_t)bh * HD * HW + cb * 512 + half * 256;
        const float* kb = k + (size_t)bh * HD * HW + cb * 512 + half * 256;

        #pragma unroll
        for (int j = 0; j < 6; ++j) {
            const int idx = j * 256 + t;        // 0..1535
            const int row = idx >> 6;           // 0..23
            const int c64 = idx & 63;
            float4 qv = *(const float4*)(qb + (size_t)row * HW + c64 * 4);
            float4 kv = *(const float4*)(kb + (size_t)row * HW + c64 * 4);
            uint2 qp = make_uint2(pack2(qv.x, qv.y), pack2(qv.z, qv.w));
            uint2 kp = make_uint2(pack2(kv.x, kv.y), pack2(kv.z, kv.w));
            *(uint2*)&tile[0][row * LSTR + c64 * 2] = qp;
            *(uint2*)&tile[1][row * LSTR + c64 * 2] = kp;
            // Export packed k to kbf[bh][row][cols] (u32 units: 8192/row).
            kbf[(((size_t)(bh * HD + row)) << 13) + (cb << 8) + half * 128 + (c64 << 1)]     = kp.x;
            kbf[(((size_t)(bh * HD + row)) << 13) + (cb << 8) + half * 128 + (c64 << 1) + 1] = kp.y;
        }
        __syncthreads();

        #pragma unroll
        for (int s = 0; s < 4; ++s) {
            const int off = (wave * 64 + s * 16) >> 1;
            bf16x8 aq = *(const bf16x8*)&tile[0][rowc * LSTR + off + hi * 4];
            bf16x8 bk = *(const bf16x8*)&tile[1][rowc * LSTR + off + hi * 4];
            aQK = __builtin_amdgcn_mfma_f32_32x32x16_bf16(aq, bk, aQK, 0, 0, 0);
            aQQ = __builtin_amdgcn_mfma_f32_32x32x16_bf16(aq, aq, aQQ, 0, 0, 0);
            aKK = __builtin_amdgcn_mfma_f32_32x32x16_bf16(bk, bk, aKK, 0, 0, 0);
        }
        __syncthreads();   // LDS reuse (next half's staging / reduce scatter)
    }

    float* red = (float*)tile;
    if (m < HD) {
        #pragma unroll
        for (int r = 0; r < 16; ++r) {
            const int i = (r & 3) + 8 * (r >> 2) + 4 * hi;
            if (i < HD) {
                red[wave * 624 + i * HD + m] = aQK[r];
                if (i == m) {
                    red[wave * 624 + 576 + i] = aQQ[r];
                    red[wave * 624 + 600 + i] = aKK[r];
                }
            }
        }
    }
    __syncthreads();

    float* Srow = ws + ((size_t)bh * SPL + cb) * SROW;
    for (int e = t; e < 624; e += 256)
        st_agent(&Srow[e], red[e] + red[624 + e] + red[1248 + e] + red[1872 + e]);

    // Per-wave drain: sc1 stores retire vmcnt at the L3 coherence point.
    asm volatile("s_waitcnt vmcnt(0)" ::: "memory");
    __syncthreads();   // all waves drained before t0's count increment

    if (t == 0) {
        unsigned int old = __hip_atomic_fetch_add(&cnt[bh], 1u,
                                                  __ATOMIC_RELAXED,
                                                  __HIP_MEMORY_SCOPE_AGENT);
        lastFlag = (old == SPL - 1);
    }
    __syncthreads();
    if (!lastFlag) return;

    // ---------------- finalizer (old kB), 256 threads, LDS reuse ----------
    // sf layout: [0,624) SA | [624,648) qinv | [648,672) kinv | [672,5280) wl
    float* sf = (float*)tile;
    const int b = bh >> 3;
    const int h = bh & 7;
    const float* base = ws + (size_t)bh * SPL * SROW;

    for (int idx = t; idx < CH * HD; idx += 256) {
        int o = idx / HD, dd = idx - o * HD;
        sf[672 + idx] = w[o * CH + h * HD + dd];
    }
    for (int e = t; e < 624; e += 256) {
        float s0 = 0.f, s1 = 0.f, s2 = 0.f, s3 = 0.f;
        #pragma unroll
        for (int sp = 0; sp < SPL; sp += 4) {
            s0 += ld_agent(&base[(size_t)(sp + 0) * SROW + e]);
            s1 += ld_agent(&base[(size_t)(sp + 1) * SROW + e]);
            s2 += ld_agent(&base[(size_t)(sp + 2) * SROW + e]);
            s3 += ld_agent(&base[(size_t)(sp + 3) * SROW + e]);
        }
        sf[e] = (s0 + s1) + (s2 + s3);
    }
    __syncthreads();

    if (t < 2 * HD) {
        float inv = 1.0f / fmaxf(sqrtf(sf[576 + t]), 1e-12f);
        sf[624 + t] = inv;                     // qinv at 624, kinv at 648
    }
    __syncthreads();

    const float sc = scale[h];
    for (int e = t; e < 576; e += 256)
        sf[e] = sf[e] * sf[624 + e / HD] * sf[648 + e % HD] * sc;
    __syncthreads();

    if (t < HD) {   // softmax along j for row t
        float mx = -1e30f;
        for (int j = 0; j < HD; ++j) mx = fmaxf(mx, sf[t * HD + j]);
        float sum = 0.f;
        for (int j = 0; j < HD; ++j) {
            float v = expf(sf[t * HD + j] - mx);
            sf[t * HD + j] = v;
            sum += v;
        }
        float r = 1.0f / sum;
        for (int j = 0; j < HD; ++j) sf[t * HD + j] *= r;
    }
    __syncthreads();

    // Mo[b][o][h*24+j] = (sum_i w[o,h*24+i] * attn[i][j]) * kinv[j]  (bf16)
    for (int idx = t; idx < CH * HD; idx += 256) {
        int o = idx / HD, j = idx - o * HD;
        float v = 0.f;
        #pragma unroll
        for (int i = 0; i < HD; ++i)
            v = fmaf(sf[672 + o * HD + i], sf[i * HD + j], v);
        Mo[(size_t)b * CH * CH + (size_t)o * CH + h * HD + j] = bf16rne(v * sf[648 + j]);
    }
}

// ---------------------------------------------------------------------------
// Kernel C — R4 structure, B-source switched to kbf (bf16): staging reads
// HALF the bytes and needs no fp32->bf16 conversion. Tile O=192 x N=64,
// one barrier, 36 MFMAs. Bt layout identical to R4 (channel pairs per u32),
// filled via ushort scatter. grid (256 nblk, 4 b), block 256, 4/CU.
// ---------------------------------------------------------------------------
#define KCN 64
#define BSTR3 100   // u32 per n-row: 96 data (192 ch as bf16 pairs) + 4 pad

__global__ __launch_bounds__(256, 4) void kC(const unsigned int* __restrict__ kbf,
                                             const unsigned short* __restrict__ Mo,
                                             float* __restrict__ out) {
    __shared__ unsigned int Bt[KCN * BSTR3];   // 25.6 KB

    const int t    = threadIdx.x;
    const int lane = t & 63;
    const int wave = t >> 6;
    const int n31  = lane & 31;
    const int hi   = lane >> 5;
    const int nt   = wave & 1;          // n-tile (x32)
    const int otb  = (wave >> 1) * 3;   // first o-tile (x32) of this wave

    const int nb = blockIdx.x * KCN;
    const int b  = blockIdx.y;

    const unsigned short* Mob = Mo + (size_t)b * CH * CH;

    // Stage 64n x 192c bf16 tile from kbf: 6 uint4 loads/thread.
    // idx -> channel ch = idx>>3 (0..191), slot sl = idx&7 (8 cols each).
    unsigned short* bt16 = (unsigned short*)Bt;
    #pragma unroll
    for (int i = 0; i < 6; ++i) {
        const int idx = i * 256 + t;        // 0..1535
        const int ch  = idx >> 3;
        const int sl  = idx & 7;
        uint4 v4 = *(const uint4*)(kbf + (((size_t)(b * CH + ch)) << 13) +
                                   ((size_t)blockIdx.x << 5) + (sl << 2));
        #pragma unroll
        for (int jj = 0; jj < 8; ++jj)
            bt16[(sl * 8 + jj) * (BSTR3 * 2) + ch] = ((const unsigned short*)&v4)[jj];
    }
    __syncthreads();

    f32x16 acc[3] = {};
    #pragma unroll
    for (int kc = 0; kc < 12; ++kc) {
        bf16x8 Bf = *(const bf16x8*)&Bt[(nt * 32 + n31) * BSTR3 + kc * 8 + hi * 4];
        #pragma unroll
        for (int oi = 0; oi < 3; ++oi) {
            const unsigned short* ap =
                Mob + (size_t)((otb + oi) * 32 + n31) * CH + kc * 16 + hi * 8;
            bf16x8 Af = *(const bf16x8*)ap;
            acc[oi] = __builtin_amdgcn_mfma_f32_32x32x16_bf16(Af, Bf, acc[oi], 0, 0, 0);
        }
    }

    float* op = out + (size_t)b * CH * HW;
    const int n = nb + nt * 32 + n31;
    #pragma unroll
    for (int oi = 0; oi < 3; ++oi)
        #pragma unroll
        for (int r = 0; r < 16; ++r) {
            int o = (otb + oi) * 32 + (r & 3) + 8 * (r >> 2) + 4 * hi;
            op[(size_t)o * HW + n] = acc[oi][r];
        }
}

extern "C" void kernel_launch(void* const* d_in, const int* in_sizes, int n_in,
                              void* d_out, int out_size, void* d_ws, size_t ws_size,
                              hipStream_t stream) {
    const float* in1   = (const float*)d_in[0];
    const float* in2   = (const float*)d_in[1];
    const float* scale = (const float*)d_in[2];
    const float* projw = (const float*)d_in[3];
    float* ws  = (float*)d_ws;   // needs ~28.1 MB
    float* out = (float*)d_out;
    unsigned short* Mo = (unsigned short*)(ws + OFF_MO);
    unsigned int* cnt  = (unsigned int*)(ws + OFF_CNT);
    unsigned int* kbf  = (unsigned int*)(ws + OFF_KBF);

    // ws is poisoned each iteration by the harness -> zero the 32 semaphores.
    hipMemsetAsync((void*)cnt, 0, 32 * sizeof(unsigned int), stream);
    kA<<<dim3(32, SPL), 256, 0, stream>>>(in1, in2, scale, projw, ws, Mo, cnt, kbf);
    kC<<<dim3(HW / KCN, BATCH), 256, 0, stream>>>(kbf, Mo, out);
}